// Round 3
// baseline (242.536 us; speedup 1.0000x reference)
//
#include <hip/hip_runtime.h>
#include <hip/hip_bf16.h>
#include <hip/hip_cooperative_groups.h>

namespace cg = cooperative_groups;

#define BATCH 4096
#define DIM 4096
#define NSPLIT 64
#define ROWS_PB 128
#define BN_EPS 1e-3f

typedef __attribute__((ext_vector_type(8))) short bf16x8;
typedef __attribute__((ext_vector_type(4))) float f32x4;

__device__ inline unsigned short f2bf(float f) {
    union { float f; unsigned int u; } c; c.f = f;
    unsigned int u = c.u;
    u += 0x7FFFu + ((u >> 16) & 1u);   // round-to-nearest-even
    return (unsigned short)(u >> 16);
}

// ============================ fused cooperative ============================
// Grid = 512 blocks x 256 threads (2 blocks/CU). Block bx: split s = bx>>3,
// row-group cgp = bx&7 -> 4 sequential chunks of 128 rows. acc for all 4
// chunks stays in registers (128 VGPR); per-block column partials -> part[],
// grid.sync(), re-reduce own split's 8 partials, normalize from registers.
// Register budget kept < 256: no global prefetch regs, single LDS X buffer.
__global__ __launch_bounds__(256, 2) void fused(
    const float* __restrict__ x, const float* __restrict__ w,
    const float* __restrict__ bias, const float* __restrict__ gamma,
    const float* __restrict__ beta, float* __restrict__ out,
    float* __restrict__ part)
{
    __shared__ unsigned short wt[64][72];      // W^T of this split (bf16), +8 pad
    __shared__ unsigned short xs[128][72];     // X chunk (bf16), +8 pad
    __shared__ float bcol[64];
    __shared__ float red_s1[4][64], red_s2[4][64];
    __shared__ float scol[64], shcol[64];

    const int bx  = blockIdx.x;
    const int s   = bx >> 3;
    const int cgp = bx & 7;
    const int t   = threadIdx.x;
    const int lane = t & 63, wave = t >> 6;
    const int quad = lane >> 4, l16 = lane & 15;

    // stage W_s (64x64 fp32 -> bf16, transposed into wt[n][k])
    for (int i = t; i < 1024; i += 256) {
        int k = i >> 4, c4 = i & 15;
        float4 v = *(const float4*)(w + (size_t)(s*64 + k) * DIM + s*64 + c4*4);
        wt[c4*4 + 0][k] = f2bf(v.x);
        wt[c4*4 + 1][k] = f2bf(v.y);
        wt[c4*4 + 2][k] = f2bf(v.z);
        wt[c4*4 + 3][k] = f2bf(v.w);
    }
    if (t < 64) bcol[t] = bias[s*64 + t];
    __syncthreads();

    // persistent B fragments: B[k=quad*8+j][n=ct*16+l16] from wt rows
    bf16x8 bfrag[4][2];
    #pragma unroll
    for (int ct = 0; ct < 4; ct++)
        #pragma unroll
        for (int kk = 0; kk < 2; kk++)
            bfrag[ct][kk] = *(const bf16x8*)&wt[ct*16 + l16][kk*32 + quad*8];

    f32x4 acc[4][2][4];      // [chunk][rt][ct] = 128 VGPRs
    float s1[4], s2[4];
    #pragma unroll
    for (int ct = 0; ct < 4; ct++) { s1[ct] = 0.f; s2[ct] = 0.f; }

    for (int j = 0; j < 4; j++) {
        // stage chunk j: 128x64 fp32 -> bf16 LDS (coalesced float4 loads)
        int r0 = (cgp*4 + j) * ROWS_PB;
        #pragma unroll
        for (int it = 0; it < 8; it++) {
            int i = t + it * 256;
            int row = i >> 4, c4 = i & 15;
            float4 v = *(const float4*)(x + (size_t)(r0 + row) * DIM + s*64 + c4*4);
            ushort4 u;
            u.x = f2bf(v.x); u.y = f2bf(v.y); u.z = f2bf(v.z); u.w = f2bf(v.w);
            *(ushort4*)&xs[row][c4*4] = u;
        }
        __syncthreads();

        #pragma unroll
        for (int rt = 0; rt < 2; rt++)
            #pragma unroll
            for (int ct = 0; ct < 4; ct++) {
                float b = bcol[ct*16 + l16];
                acc[j][rt][ct] = (f32x4){b, b, b, b};
            }

        // A fragments: A[m=l16][k=quad*8+jj] from xs rows
        bf16x8 af[2][2];
        #pragma unroll
        for (int rt = 0; rt < 2; rt++)
            #pragma unroll
            for (int kk = 0; kk < 2; kk++)
                af[rt][kk] = *(const bf16x8*)&xs[wave*32 + rt*16 + l16][kk*32 + quad*8];

        #pragma unroll
        for (int kk = 0; kk < 2; kk++)
            #pragma unroll
            for (int rt = 0; rt < 2; rt++)
                #pragma unroll
                for (int ct = 0; ct < 4; ct++)
                    acc[j][rt][ct] = __builtin_amdgcn_mfma_f32_16x16x32_bf16(
                        af[rt][kk], bfrag[ct][kk], acc[j][rt][ct], 0, 0, 0);

        #pragma unroll
        for (int rt = 0; rt < 2; rt++)
            #pragma unroll
            for (int ct = 0; ct < 4; ct++)
                #pragma unroll
                for (int r = 0; r < 4; r++) {
                    float v = acc[j][rt][ct][r];
                    s1[ct] += v; s2[ct] += v * v;
                }
        __syncthreads();   // before next chunk overwrites xs
    }

    // block-level column reduction -> part[bx][0:64]=sum, [64:128]=sumsq
    #pragma unroll
    for (int ct = 0; ct < 4; ct++) {
        float a = s1[ct], b = s2[ct];
        a += __shfl_xor(a, 16); b += __shfl_xor(b, 16);
        a += __shfl_xor(a, 32); b += __shfl_xor(b, 32);
        if (quad == 0) {
            red_s1[wave][ct*16 + l16] = a;
            red_s2[wave][ct*16 + l16] = b;
        }
    }
    __syncthreads();
    if (t < 64) {
        float a = red_s1[0][t] + red_s1[1][t] + red_s1[2][t] + red_s1[3][t];
        float b = red_s2[0][t] + red_s2[1][t] + red_s2[2][t] + red_s2[3][t];
        part[(size_t)bx * 128 + t]      = a;
        part[(size_t)bx * 128 + 64 + t] = b;
    }

    cg::this_grid().sync();

    if (t < 64) {
        float a = 0.f, b = 0.f;
        #pragma unroll
        for (int i = 0; i < 8; i++) {
            a += part[(size_t)(s*8 + i) * 128 + t];
            b += part[(size_t)(s*8 + i) * 128 + 64 + t];
        }
        float mean = a * (1.f / BATCH);
        float var  = b * (1.f / BATCH) - mean * mean;
        float rstd = rsqrtf(var + BN_EPS);
        float sc = gamma[s*64 + t] * rstd;
        scol[t]  = sc;
        shcol[t] = beta[s*64 + t] - mean * sc;
    }
    __syncthreads();

    #pragma unroll
    for (int j = 0; j < 4; j++)
        #pragma unroll
        for (int rt = 0; rt < 2; rt++)
            #pragma unroll
            for (int ct = 0; ct < 4; ct++) {
                int col = ct*16 + l16;
                float sc = scol[col], sh = shcol[col];
                #pragma unroll
                for (int r = 0; r < 4; r++) {
                    float v = fmaxf(fmaf(acc[j][rt][ct][r], sc, sh), 0.f);
                    int row = cgp*512 + j*128 + wave*32 + rt*16 + quad*4 + r;
                    out[(size_t)row * DIM + s*64 + col] = v;
                }
            }
}

// ======================= fallback (proven R1 path) =========================
__global__ __launch_bounds__(256) void gemm_stats(
    const float* __restrict__ x, const float* __restrict__ w,
    const float* __restrict__ bias,
    unsigned short* __restrict__ wsout,
    float* __restrict__ gsum, float* __restrict__ gsumsq)
{
    __shared__ unsigned short xs[ROWS_PB][72];
    __shared__ unsigned short wt[64][72];
    __shared__ float bcol[64];
    __shared__ float csum[64], csumsq[64];

    const int s  = blockIdx.y;
    const int r0 = blockIdx.x * ROWS_PB;
    const int t  = threadIdx.x;

    if (t < 64) { bcol[t] = bias[s*64 + t]; csum[t] = 0.f; csumsq[t] = 0.f; }

    for (int i = t; i < ROWS_PB * 16; i += 256) {
        int row = i >> 4, c4 = i & 15;
        float4 v = *(const float4*)(x + (size_t)(r0 + row) * DIM + s*64 + c4*4);
        ushort4 u;
        u.x = f2bf(v.x); u.y = f2bf(v.y); u.z = f2bf(v.z); u.w = f2bf(v.w);
        *(ushort4*)&xs[row][c4 * 4] = u;
    }
    for (int i = t; i < 64 * 64; i += 256) {
        int k = i >> 6, n = i & 63;
        wt[n][k] = f2bf(w[(size_t)(s*64 + k) * DIM + s*64 + n]);
    }
    __syncthreads();

    const int lane = t & 63, wave = t >> 6;
    const int quad = lane >> 4, l16 = lane & 15;
    const int wrow = wave * 32;

    f32x4 acc[2][4];
    for (int rt = 0; rt < 2; rt++)
        for (int ct = 0; ct < 4; ct++) {
            float b = bcol[ct*16 + l16];
            acc[rt][ct] = (f32x4){b, b, b, b};
        }

    bf16x8 afrag[2][2], bfrag[4][2];
    for (int rt = 0; rt < 2; rt++)
        for (int kk = 0; kk < 2; kk++)
            afrag[rt][kk] = *(const bf16x8*)&xs[wrow + rt*16 + l16][kk*32 + quad*8];
    for (int ct = 0; ct < 4; ct++)
        for (int kk = 0; kk < 2; kk++)
            bfrag[ct][kk] = *(const bf16x8*)&wt[ct*16 + l16][kk*32 + quad*8];

    for (int kk = 0; kk < 2; kk++)
        for (int rt = 0; rt < 2; rt++)
            for (int ct = 0; ct < 4; ct++)
                acc[rt][ct] = __builtin_amdgcn_mfma_f32_16x16x32_bf16(
                    afrag[rt][kk], bfrag[ct][kk], acc[rt][ct], 0, 0, 0);

    float s1[4], s2[4];
    for (int ct = 0; ct < 4; ct++) { s1[ct] = 0.f; s2[ct] = 0.f; }
    for (int rt = 0; rt < 2; rt++)
        for (int ct = 0; ct < 4; ct++) {
            int col = ct*16 + l16;
            for (int r = 0; r < 4; r++) {
                float v = acc[rt][ct][r];
                int row = r0 + wrow + rt*16 + quad*4 + r;
                wsout[(size_t)row * DIM + s*64 + col] = f2bf(v);
                s1[ct] += v; s2[ct] += v * v;
            }
        }
    for (int ct = 0; ct < 4; ct++) {
        float a = s1[ct], b = s2[ct];
        a += __shfl_xor(a, 16); b += __shfl_xor(b, 16);
        a += __shfl_xor(a, 32); b += __shfl_xor(b, 32);
        if (quad == 0) {
            atomicAdd(&csum[ct*16 + l16], a);
            atomicAdd(&csumsq[ct*16 + l16], b);
        }
    }
    __syncthreads();
    if (t < 64) {
        atomicAdd(&gsum[s*64 + t], csum[t]);
        atomicAdd(&gsumsq[s*64 + t], csumsq[t]);
    }
}

__global__ __launch_bounds__(256) void finalize_stats(
    const float* __restrict__ gsum, const float* __restrict__ gsumsq,
    const float* __restrict__ gamma, const float* __restrict__ beta,
    float* __restrict__ scale, float* __restrict__ shiftv)
{
    int j = blockIdx.x * 256 + threadIdx.x;
    float mean = gsum[j] * (1.f / BATCH);
    float var  = gsumsq[j] * (1.f / BATCH) - mean * mean;
    float rstd = rsqrtf(var + BN_EPS);
    float sc = gamma[j] * rstd;
    scale[j]  = sc;
    shiftv[j] = beta[j] - mean * sc;
}

__global__ __launch_bounds__(256) void normalize(
    const unsigned short* __restrict__ wsout,
    const float* __restrict__ scale, const float* __restrict__ shiftv,
    float* __restrict__ out)
{
    size_t i = ((size_t)blockIdx.x * 256 + threadIdx.x) * 8;
    int col = (int)(i & (DIM - 1));
    uint4 u = *(const uint4*)(wsout + i);
    float4 sc0 = *(const float4*)(scale + col);
    float4 sc1 = *(const float4*)(scale + col + 4);
    float4 sh0 = *(const float4*)(shiftv + col);
    float4 sh1 = *(const float4*)(shiftv + col + 4);
    float v0 = __uint_as_float(u.x << 16), v1 = __uint_as_float(u.x & 0xFFFF0000u);
    float v2 = __uint_as_float(u.y << 16), v3 = __uint_as_float(u.y & 0xFFFF0000u);
    float v4 = __uint_as_float(u.z << 16), v5 = __uint_as_float(u.z & 0xFFFF0000u);
    float v6 = __uint_as_float(u.w << 16), v7 = __uint_as_float(u.w & 0xFFFF0000u);
    float4 o0, o1;
    o0.x = fmaxf(fmaf(v0, sc0.x, sh0.x), 0.f);
    o0.y = fmaxf(fmaf(v1, sc0.y, sh0.y), 0.f);
    o0.z = fmaxf(fmaf(v2, sc0.z, sh0.z), 0.f);
    o0.w = fmaxf(fmaf(v3, sc0.w, sh0.w), 0.f);
    o1.x = fmaxf(fmaf(v4, sc1.x, sh1.x), 0.f);
    o1.y = fmaxf(fmaf(v5, sc1.y, sh1.y), 0.f);
    o1.z = fmaxf(fmaf(v6, sc1.z, sh1.z), 0.f);
    o1.w = fmaxf(fmaf(v7, sc1.w, sh1.w), 0.f);
    *(float4*)(out + i)     = o0;
    *(float4*)(out + i + 4) = o1;
}

extern "C" void kernel_launch(void* const* d_in, const int* in_sizes, int n_in,
                              void* d_out, int out_size, void* d_ws, size_t ws_size,
                              hipStream_t stream) {
    const float* x     = (const float*)d_in[0];
    const float* w     = (const float*)d_in[1];
    const float* bias  = (const float*)d_in[2];
    const float* gamma = (const float*)d_in[3];
    const float* beta  = (const float*)d_in[4];
    float* out  = (float*)d_out;
    float* part = (float*)d_ws;   // coop path: 512 x 128 floats, written before read

    void* args[] = {(void*)&x, (void*)&w, (void*)&bias, (void*)&gamma,
                    (void*)&beta, (void*)&out, (void*)&part};
    hipError_t err = hipLaunchCooperativeKernel((void*)fused, dim3(512), dim3(256),
                                                args, 0, stream);
    if (err != hipSuccess) {
        // fallback: proven 3-kernel path (R1), disjoint-free ws layout
        unsigned short* wsout = (unsigned short*)d_ws;
        float* gsum   = (float*)((char*)d_ws + (size_t)BATCH * DIM * 2);
        float* gsumsq = gsum + DIM;
        float* scale  = gsum + 2 * DIM;
        float* shiftv = gsum + 3 * DIM;
        hipMemsetAsync(gsum, 0, 2 * DIM * sizeof(float), stream);
        gemm_stats<<<dim3(BATCH / ROWS_PB, NSPLIT), 256, 0, stream>>>(
            x, w, bias, wsout, gsum, gsumsq);
        finalize_stats<<<DIM / 256, 256, 0, stream>>>(gsum, gsumsq, gamma, beta,
                                                      scale, shiftv);
        normalize<<<(size_t)BATCH * DIM / 8 / 256, 256, 0, stream>>>(
            wsout, scale, shiftv, out);
    }
}

// Round 4
// 185.726 us; speedup vs baseline: 1.3059x; 1.3059x over previous
//
#include <hip/hip_runtime.h>
#include <hip/hip_bf16.h>

#define BATCH 4096
#define DIM 4096
#define NSPLIT 64
#define ROWS_PB 128
#define NCHUNK 32            // BATCH / ROWS_PB
#define BN_EPS 1e-3f

typedef __attribute__((ext_vector_type(8))) short bf16x8;
typedef __attribute__((ext_vector_type(4))) float f32x4;

__device__ inline unsigned short f2bf(float f) {
    union { float f; unsigned int u; } c; c.f = f;
    unsigned int u = c.u;
    u += 0x7FFFu + ((u >> 16) & 1u);   // round-to-nearest-even
    return (unsigned short)(u >> 16);
}

// Pass 1: GEMM (results discarded) + per-block column sum/sumsq partials.
// part[(s*NCHUNK+chunk)*128 + 0:64] = sum, [64:128] = sumsq. Plain stores:
// no atomics, no memset needed.
__global__ __launch_bounds__(256) void stats_pass(
    const float* __restrict__ x, const float* __restrict__ w,
    const float* __restrict__ bias, float* __restrict__ part)
{
    __shared__ unsigned short xs[ROWS_PB][72];   // +8 pad: 2-way aliasing only (free)
    __shared__ unsigned short wt[64][72];
    __shared__ float bcol[64];
    __shared__ float red1[4][64], red2[4][64];

    const int s  = blockIdx.y;
    const int r0 = blockIdx.x * ROWS_PB;
    const int t  = threadIdx.x;
    const int lane = t & 63, wave = t >> 6;
    const int quad = lane >> 4, l16 = lane & 15;

    // stage W_s transposed (fp32 -> bf16), coalesced float4 reads
    for (int i = t; i < 1024; i += 256) {
        int k = i >> 4, c4 = i & 15;
        float4 v = *(const float4*)(w + (size_t)(s*64 + k) * DIM + s*64 + c4*4);
        wt[c4*4 + 0][k] = f2bf(v.x);
        wt[c4*4 + 1][k] = f2bf(v.y);
        wt[c4*4 + 2][k] = f2bf(v.z);
        wt[c4*4 + 3][k] = f2bf(v.w);
    }
    if (t < 64) bcol[t] = bias[s*64 + t];

    // stage X chunk (128x64 fp32 -> bf16)
    #pragma unroll
    for (int it = 0; it < 8; it++) {
        int i = t + it * 256;
        int row = i >> 4, c4 = i & 15;
        float4 v = *(const float4*)(x + (size_t)(r0 + row) * DIM + s*64 + c4*4);
        ushort4 u;
        u.x = f2bf(v.x); u.y = f2bf(v.y); u.z = f2bf(v.z); u.w = f2bf(v.w);
        *(ushort4*)&xs[row][c4*4] = u;
    }
    __syncthreads();

    f32x4 acc[2][4];
    #pragma unroll
    for (int rt = 0; rt < 2; rt++)
        #pragma unroll
        for (int ct = 0; ct < 4; ct++) {
            float b = bcol[ct*16 + l16];
            acc[rt][ct] = (f32x4){b, b, b, b};
        }

    bf16x8 af[2][2], bf[4][2];
    #pragma unroll
    for (int rt = 0; rt < 2; rt++)
        #pragma unroll
        for (int kk = 0; kk < 2; kk++)
            af[rt][kk] = *(const bf16x8*)&xs[wave*32 + rt*16 + l16][kk*32 + quad*8];
    #pragma unroll
    for (int ct = 0; ct < 4; ct++)
        #pragma unroll
        for (int kk = 0; kk < 2; kk++)
            bf[ct][kk] = *(const bf16x8*)&wt[ct*16 + l16][kk*32 + quad*8];

    #pragma unroll
    for (int kk = 0; kk < 2; kk++)
        #pragma unroll
        for (int rt = 0; rt < 2; rt++)
            #pragma unroll
            for (int ct = 0; ct < 4; ct++)
                acc[rt][ct] = __builtin_amdgcn_mfma_f32_16x16x32_bf16(
                    af[rt][kk], bf[ct][kk], acc[rt][ct], 0, 0, 0);

    // per-thread column partials -> wave shuffle -> cross-wave LDS -> ws
    float s1[4], s2[4];
    #pragma unroll
    for (int ct = 0; ct < 4; ct++) { s1[ct] = 0.f; s2[ct] = 0.f; }
    #pragma unroll
    for (int rt = 0; rt < 2; rt++)
        #pragma unroll
        for (int ct = 0; ct < 4; ct++)
            #pragma unroll
            for (int r = 0; r < 4; r++) {
                float v = acc[rt][ct][r];
                s1[ct] += v; s2[ct] += v * v;
            }
    #pragma unroll
    for (int ct = 0; ct < 4; ct++) {
        float a = s1[ct], b = s2[ct];
        a += __shfl_xor(a, 16); b += __shfl_xor(b, 16);
        a += __shfl_xor(a, 32); b += __shfl_xor(b, 32);
        if (quad == 0) {
            red1[wave][ct*16 + l16] = a;
            red2[wave][ct*16 + l16] = b;
        }
    }
    __syncthreads();
    if (t < 64) {
        float a = red1[0][t] + red1[1][t] + red1[2][t] + red1[3][t];
        float b = red2[0][t] + red2[1][t] + red2[2][t] + red2[3][t];
        size_t base = (size_t)(s * NCHUNK + blockIdx.x) * 128;
        part[base + t]      = a;
        part[base + 64 + t] = b;
    }
}

// Pass 2: GEMM again + in-block stats finalize + BN + ReLU + fp32 store.
__global__ __launch_bounds__(256) void main_pass(
    const float* __restrict__ x, const float* __restrict__ w,
    const float* __restrict__ bias, const float* __restrict__ gamma,
    const float* __restrict__ beta, const float* __restrict__ part,
    float* __restrict__ out)
{
    __shared__ unsigned short xs[ROWS_PB][72];
    __shared__ unsigned short wt[64][72];
    __shared__ float bcol[64];
    __shared__ float scol[64], shcol[64];

    const int s  = blockIdx.y;
    const int r0 = blockIdx.x * ROWS_PB;
    const int t  = threadIdx.x;
    const int lane = t & 63, wave = t >> 6;
    const int quad = lane >> 4, l16 = lane & 15;

    // stage W_s transposed
    for (int i = t; i < 1024; i += 256) {
        int k = i >> 4, c4 = i & 15;
        float4 v = *(const float4*)(w + (size_t)(s*64 + k) * DIM + s*64 + c4*4);
        wt[c4*4 + 0][k] = f2bf(v.x);
        wt[c4*4 + 1][k] = f2bf(v.y);
        wt[c4*4 + 2][k] = f2bf(v.z);
        wt[c4*4 + 3][k] = f2bf(v.w);
    }
    if (t < 64) bcol[t] = bias[s*64 + t];

    // stage X chunk
    #pragma unroll
    for (int it = 0; it < 8; it++) {
        int i = t + it * 256;
        int row = i >> 4, c4 = i & 15;
        float4 v = *(const float4*)(x + (size_t)(r0 + row) * DIM + s*64 + c4*4);
        ushort4 u;
        u.x = f2bf(v.x); u.y = f2bf(v.y); u.z = f2bf(v.z); u.w = f2bf(v.w);
        *(ushort4*)&xs[row][c4*4] = u;
    }

    // reduce this split's 32 partials -> scale/shift (redundant per block, cheap)
    if (t < 64) {
        float a = 0.f, b = 0.f;
        #pragma unroll 8
        for (int p = 0; p < NCHUNK; p++) {
            size_t base = (size_t)(s * NCHUNK + p) * 128;
            a += part[base + t];
            b += part[base + 64 + t];
        }
        float mean = a * (1.f / BATCH);
        float var  = b * (1.f / BATCH) - mean * mean;
        float rstd = rsqrtf(var + BN_EPS);
        float sc = gamma[s*64 + t] * rstd;
        scol[t]  = sc;
        shcol[t] = beta[s*64 + t] - mean * sc;
    }
    __syncthreads();

    f32x4 acc[2][4];
    #pragma unroll
    for (int rt = 0; rt < 2; rt++)
        #pragma unroll
        for (int ct = 0; ct < 4; ct++) {
            float b = bcol[ct*16 + l16];
            acc[rt][ct] = (f32x4){b, b, b, b};
        }

    bf16x8 af[2][2], bf[4][2];
    #pragma unroll
    for (int rt = 0; rt < 2; rt++)
        #pragma unroll
        for (int kk = 0; kk < 2; kk++)
            af[rt][kk] = *(const bf16x8*)&xs[wave*32 + rt*16 + l16][kk*32 + quad*8];
    #pragma unroll
    for (int ct = 0; ct < 4; ct++)
        #pragma unroll
        for (int kk = 0; kk < 2; kk++)
            bf[ct][kk] = *(const bf16x8*)&wt[ct*16 + l16][kk*32 + quad*8];

    #pragma unroll
    for (int kk = 0; kk < 2; kk++)
        #pragma unroll
        for (int rt = 0; rt < 2; rt++)
            #pragma unroll
            for (int ct = 0; ct < 4; ct++)
                acc[rt][ct] = __builtin_amdgcn_mfma_f32_16x16x32_bf16(
                    af[rt][kk], bf[ct][kk], acc[rt][ct], 0, 0, 0);

    // normalize + ReLU + store fp32
    #pragma unroll
    for (int rt = 0; rt < 2; rt++)
        #pragma unroll
        for (int ct = 0; ct < 4; ct++) {
            int col = ct*16 + l16;
            float sc = scol[col], sh = shcol[col];
            #pragma unroll
            for (int r = 0; r < 4; r++) {
                float v = fmaxf(fmaf(acc[rt][ct][r], sc, sh), 0.f);
                int row = r0 + wave*32 + rt*16 + quad*4 + r;
                out[(size_t)row * DIM + s*64 + col] = v;
            }
        }
}

extern "C" void kernel_launch(void* const* d_in, const int* in_sizes, int n_in,
                              void* d_out, int out_size, void* d_ws, size_t ws_size,
                              hipStream_t stream) {
    const float* x     = (const float*)d_in[0];
    const float* w     = (const float*)d_in[1];
    const float* bias  = (const float*)d_in[2];
    const float* gamma = (const float*)d_in[3];
    const float* beta  = (const float*)d_in[4];
    float* out  = (float*)d_out;
    float* part = (float*)d_ws;    // 2048 * 128 floats = 1 MB, fully written by K1

    stats_pass<<<dim3(NCHUNK, NSPLIT), 256, 0, stream>>>(x, w, bias, part);
    main_pass<<<dim3(NCHUNK, NSPLIT), 256, 0, stream>>>(x, w, bias, gamma, beta,
                                                        part, out);
}